// Round 1
// baseline (1093.686 us; speedup 1.0000x reference)
//
#include <hip/hip_runtime.h>
#include <hip/hip_bf16.h>
#include <stdint.h>
#include <stddef.h>

// ---------------------------------------------------------------------------
// BasicMambaBlock on MI355X (gfx950).
// Pipeline: LN1 -> GEMM(w_in) -> conv+silu -> GEMM(w_x) -> GEMM(w_dt)+softplus
//           -> selective scan -> GEMM(w_out)+res -> LN2 -> GEMM(w_ff1)+bias
//           -> geglu -> GEMM(w_ff2)+bias+res.
// All big GEMMs: bf16 MFMA 16x16x32, 128x128 tile, 4 waves, global_load_lds.
// Weights transposed to [N][K] bf16 once per call (inputs restored each call).
// ---------------------------------------------------------------------------

typedef __bf16 bf16;
typedef __bf16 bf16x8 __attribute__((ext_vector_type(8)));
typedef float  f32x4  __attribute__((ext_vector_type(4)));

static constexpr int kB  = 2;
static constexpr int kL  = 2048;
static constexpr int kDM = 1024;          // d_model
static constexpr int kDI = 2048;          // d_inner
static constexpr int kM  = kB * kL;       // 4096 rows (B*L)

// ---------------- helpers ----------------
__device__ __forceinline__ void gload16(const void* g, void* l) {
  // async global->LDS, 16B per lane; LDS dest = (wave-uniform l) + lane*16
  __builtin_amdgcn_global_load_lds((__attribute__((address_space(1))) void*)g,
                                   (__attribute__((address_space(3))) void*)l,
                                   16, 0, 0);
}

// ---------------- weight transpose fp32[K][N] -> bf16[Npad][K] --------------
__global__ __launch_bounds__(256) void transpose_to_bf16(
    const float* __restrict__ w, bf16* __restrict__ wt, int K, int N, int Npad) {
  __shared__ float t[32][33];
  const int k0 = blockIdx.x * 32, n0 = blockIdx.y * 32;
  const int tx = threadIdx.x & 31, ty = threadIdx.x >> 5;  // 32 x 8
#pragma unroll
  for (int i = ty; i < 32; i += 8) {
    float v = 0.f;
    if (k0 + i < K && n0 + tx < N) v = w[(size_t)(k0 + i) * N + n0 + tx];
    t[i][tx] = v;
  }
  __syncthreads();
#pragma unroll
  for (int i = ty; i < 32; i += 8) {
    const int n = n0 + i, k = k0 + tx;
    if (n < Npad && k < K) wt[(size_t)n * K + k] = (bf16)t[tx][i];
  }
}

// ---------------- layernorm (D=1024) -> bf16 ----------------
__global__ __launch_bounds__(256) void layernorm_to_bf16(
    const float* __restrict__ x, const float* __restrict__ g,
    const float* __restrict__ b, bf16* __restrict__ out) {
  const int row = blockIdx.x;
  const float4 v = ((const float4*)(x + (size_t)row * kDM))[threadIdx.x];
  float s  = v.x + v.y + v.z + v.w;
  float s2 = v.x * v.x + v.y * v.y + v.z * v.z + v.w * v.w;
#pragma unroll
  for (int off = 1; off < 64; off <<= 1) {
    s  += __shfl_xor(s, off);
    s2 += __shfl_xor(s2, off);
  }
  __shared__ float ws[4], ws2[4];
  const int wave = threadIdx.x >> 6, lane = threadIdx.x & 63;
  if (lane == 0) { ws[wave] = s; ws2[wave] = s2; }
  __syncthreads();
  s  = ws[0] + ws[1] + ws[2] + ws[3];
  s2 = ws2[0] + ws2[1] + ws2[2] + ws2[3];
  const float mu  = s * (1.f / kDM);
  const float var = s2 * (1.f / kDM) - mu * mu;
  const float r   = rsqrtf(var + 1e-5f);
  const int c = threadIdx.x * 4;
  const float4 gg = ((const float4*)g)[threadIdx.x];
  const float4 bb = ((const float4*)b)[threadIdx.x];
  bf16* o = out + (size_t)row * kDM + c;
  o[0] = (bf16)((v.x - mu) * r * gg.x + bb.x);
  o[1] = (bf16)((v.y - mu) * r * gg.y + bb.y);
  o[2] = (bf16)((v.z - mu) * r * gg.z + bb.z);
  o[3] = (bf16)((v.w - mu) * r * gg.w + bb.w);
}

// ---------------- bf16 MFMA GEMM: C[M][N] = A[M][K] * BT[N][K]^T ------------
// 128x128 tile, 4 waves (each 64x64 = 4x4 16x16 frags), BK=32, linear LDS,
// global_load_lds width-16 staging (m97 structure).
template <int MODE>
__global__ __launch_bounds__(256, 2) void gemm_bt(
    const bf16* __restrict__ A, int lda,
    const bf16* __restrict__ BT, int ldbt, int K,
    float* __restrict__ C0, bf16* __restrict__ C1,
    const float* __restrict__ bias, const float* __restrict__ res) {
  __shared__ __align__(16) bf16 As[128 * 32];
  __shared__ __align__(16) bf16 Bs[128 * 32];

  const int tid  = threadIdx.x;
  const int wave = tid >> 6;
  const int lane = tid & 63;
  const int m0 = blockIdx.y * 128;
  const int n0 = blockIdx.x * 128;
  const int wr = wave >> 1, wc = wave & 1;       // 2x2 wave grid, 64x64 each
  const int lr = lane & 15, kg = lane >> 4;

  const int srow = lane >> 2;                    // staging row within chunk
  const int scol = (lane & 3) * 8;               // staging col (bf16 elems)

  const bf16* Ag0 = A  + (size_t)(m0 + wave * 32 + srow) * lda  + scol;
  const bf16* Ag1 = Ag0 + (size_t)16 * lda;
  const bf16* Bg0 = BT + (size_t)(n0 + wave * 32 + srow) * ldbt + scol;
  const bf16* Bg1 = Bg0 + (size_t)16 * ldbt;
  bf16* Al0 = As + wave * 1024;  // wave stages rows [32w, 32w+32)
  bf16* Al1 = Al0 + 512;
  bf16* Bl0 = Bs + wave * 1024;
  bf16* Bl1 = Bl0 + 512;

  f32x4 acc[4][4] = {};

  for (int kt = 0; kt < K; kt += 32) {
    __syncthreads();                              // protect LDS from prev reads
    gload16(Ag0 + kt, Al0);
    gload16(Ag1 + kt, Al1);
    gload16(Bg0 + kt, Bl0);
    gload16(Bg1 + kt, Bl1);
    __syncthreads();                              // compiler drains vmcnt here

    bf16x8 af[4], bfr[4];
#pragma unroll
    for (int i = 0; i < 4; ++i) {
      af[i]  = *(const bf16x8*)(As + (wr * 64 + i * 16 + lr) * 32 + kg * 8);
      bfr[i] = *(const bf16x8*)(Bs + (wc * 64 + i * 16 + lr) * 32 + kg * 8);
    }
#pragma unroll
    for (int i = 0; i < 4; ++i)
#pragma unroll
      for (int j = 0; j < 4; ++j)
        acc[i][j] =
            __builtin_amdgcn_mfma_f32_16x16x32_bf16(af[i], bfr[j], acc[i][j], 0, 0, 0);
  }

  // epilogue: C/D layout col=lane&15, row=(lane>>4)*4+e  [verified m89]
#pragma unroll
  for (int i = 0; i < 4; ++i) {
    const int mbase = m0 + wr * 64 + i * 16 + kg * 4;
#pragma unroll
    for (int j = 0; j < 4; ++j) {
      const int n = n0 + wc * 64 + j * 16 + lr;
#pragma unroll
      for (int e = 0; e < 4; ++e) {
        const int m = mbase + e;
        const float v = acc[i][j][e];
        if constexpr (MODE == 0) {        // xz: cols<2048 raw xc, else silu(z)
          if (n < kDI) C0[(size_t)m * kDI + n] = v;
          else         C1[(size_t)m * kDI + (n - kDI)] = (bf16)(v / (1.f + expf(-v)));
        } else if constexpr (MODE == 1) { // dbc fp32 (+ bf16 dt_lo for cols<64)
          C0[(size_t)m * 128 + n] = v;
          if (n < 64) C1[(size_t)m * 64 + n] = (bf16)v;
        } else if constexpr (MODE == 2) { // dt = softplus(v + b_dt)
          const float t = v + bias[n];
          const float sp = (t > 0.f) ? (t + log1pf(expf(-t))) : log1pf(expf(t));
          C0[(size_t)m * kDI + n] = sp;
        } else if constexpr (MODE == 3) { // out1 = x + mamba_out
          C0[(size_t)m * kDM + n] = v + res[(size_t)m * kDM + n];
        } else if constexpr (MODE == 4) { // p = v + b_ff1 (bf16)
          C1[(size_t)m * 8192 + n] = (bf16)(v + bias[n]);
        } else {                          // MODE 5: d_out = v + b_ff2 + out1
          C0[(size_t)m * kDM + n] = v + bias[n] + res[(size_t)m * kDM + n];
        }
      }
    }
  }
}

// ---------------- depthwise causal conv (D_CONV=4) + silu ----------------
__global__ __launch_bounds__(256) void conv_silu(
    const float* __restrict__ xc_raw, const float* __restrict__ cw,
    const float* __restrict__ cb, float* __restrict__ xf, bf16* __restrict__ xb) {
  const int idx = blockIdx.x * 256 + threadIdx.x;  // over M*DI
  const int d = idx & (kDI - 1);
  const int m = idx >> 11;
  const int l = m & (kL - 1);
  float acc = cb[d];
  const float w0 = cw[d * 4 + 0], w1 = cw[d * 4 + 1], w2 = cw[d * 4 + 2],
              w3 = cw[d * 4 + 3];
  if (l >= 3) acc += xc_raw[(size_t)(m - 3) * kDI + d] * w0;
  if (l >= 2) acc += xc_raw[(size_t)(m - 2) * kDI + d] * w1;
  if (l >= 1) acc += xc_raw[(size_t)(m - 1) * kDI + d] * w2;
  acc += xc_raw[(size_t)m * kDI + d] * w3;
  const float a = acc / (1.f + expf(-acc));        // silu
  xf[idx] = a;
  xb[idx] = (bf16)a;
}

// ---------------- selective scan ----------------
// 16 lanes per (b,d) channel (one per state n); 2-deep 8-step reg prefetch.
__global__ __launch_bounds__(256) void mamba_scan(
    const float* __restrict__ dt,    // [M][DI]
    const float* __restrict__ xc,    // [M][DI]   (post conv+silu)
    const float* __restrict__ dbc,   // [M][128]  B at 64+n, C at 80+n
    const float* __restrict__ a_log, // [DI][16]
    const float* __restrict__ d_skip,
    const bf16* __restrict__ zs,     // [M][DI]   silu(z)
    bf16* __restrict__ y) {          // [M][DI]
  const int b  = blockIdx.x >> 7;
  const int d0 = (blockIdx.x & 127) * 16;
  const int dl = threadIdx.x >> 4;
  const int n  = threadIdx.x & 15;
  const int d  = d0 + dl;
  const float Adn = -expf(a_log[d * 16 + n]);
  const float dsk = d_skip[d];
  const size_t rb = (size_t)b * kL * kDI + d;   // row base (advance by l*kDI)
  const size_t qb = (size_t)b * kL * 128;

  float dtA[8], xA[8], BA[8], CA[8], zA[8];
  float dtB[8], xB[8], BB_[8], CB[8], zB[8];

#define LOADC(DT, X, BV, CV, ZV, l0)                               \
  {                                                                \
    _Pragma("unroll") for (int u = 0; u < 8; ++u) {                \
      const size_t r = rb + (size_t)((l0) + u) * kDI;              \
      const size_t q = qb + (size_t)((l0) + u) * 128;              \
      DT[u] = dt[r];  X[u] = xc[r];                                \
      BV[u] = dbc[q + 64 + n];  CV[u] = dbc[q + 80 + n];           \
      ZV[u] = (float)zs[r];                                        \
    }                                                              \
  }
#define COMP(DT, X, BV, CV, ZV, l0)                                \
  {                                                                \
    _Pragma("unroll") for (int u = 0; u < 8; ++u) {                \
      const float dA = __expf(DT[u] * Adn);                        \
      h = h * dA + DT[u] * X[u] * BV[u];                           \
      float part = h * CV[u];                                      \
      part += __shfl_xor(part, 1);                                 \
      part += __shfl_xor(part, 2);                                 \
      part += __shfl_xor(part, 4);                                 \
      part += __shfl_xor(part, 8);                                 \
      if (n == 0) {                                                \
        const size_t r = rb + (size_t)((l0) + u) * kDI;            \
        y[r] = (bf16)((part + dsk * X[u]) * ZV[u]);                \
      }                                                            \
    }                                                              \
  }

  float h = 0.f;
  LOADC(dtA, xA, BA, CA, zA, 0);
  for (int l0 = 0; l0 < kL; l0 += 16) {
    LOADC(dtB, xB, BB_, CB, zB, l0 + 8);
    COMP(dtA, xA, BA, CA, zA, l0);
    if (l0 + 16 < kL) LOADC(dtA, xA, BA, CA, zA, l0 + 16);
    COMP(dtB, xB, BB_, CB, zB, l0 + 8);
  }
#undef LOADC
#undef COMP
}

// ---------------- geglu: v = a * gelu_tanh(g) ----------------
__global__ __launch_bounds__(256) void geglu(
    const bf16* __restrict__ p, bf16* __restrict__ v) {
  const int idx = blockIdx.x * 256 + threadIdx.x;  // over M*4096
  const int m = idx >> 12, n = idx & 4095;
  const float a = (float)p[(size_t)m * 8192 + n];
  const float g = (float)p[(size_t)m * 8192 + 4096 + n];
  const float g3 = g * g * g;
  const float t  = tanhf(0.7978845608028654f * (g + 0.044715f * g3));
  v[idx] = (bf16)(a * (0.5f * g * (1.f + t)));
}

// ---------------- launch ----------------
extern "C" void kernel_launch(void* const* d_in, const int* in_sizes, int n_in,
                              void* d_out, int out_size, void* d_ws, size_t ws_size,
                              hipStream_t stream) {
  const float* x      = (const float*)d_in[0];
  const float* ln1_g  = (const float*)d_in[1];
  const float* ln1_b  = (const float*)d_in[2];
  const float* w_in   = (const float*)d_in[3];
  const float* conv_w = (const float*)d_in[4];
  const float* conv_b = (const float*)d_in[5];
  const float* w_x    = (const float*)d_in[6];
  const float* w_dt   = (const float*)d_in[7];
  const float* b_dt   = (const float*)d_in[8];
  const float* a_log  = (const float*)d_in[9];
  const float* d_skip = (const float*)d_in[10];
  const float* w_out  = (const float*)d_in[11];
  const float* ln2_g  = (const float*)d_in[12];
  const float* ln2_b  = (const float*)d_in[13];
  const float* w_ff1  = (const float*)d_in[14];
  const float* b_ff1  = (const float*)d_in[15];
  const float* w_ff2  = (const float*)d_in[16];
  const float* b_ff2  = (const float*)d_in[17];
  float* out = (float*)d_out;
  char* ws = (char*)d_ws;

  // arena layout (bytes); lifetimes allow the noted aliasing
  bf16* wT_in  = (bf16*)(ws + 0);          //  8 MiB [4096][1024]
  bf16* wT_x   = (bf16*)(ws + 8388608);    //  0.5 MiB [128][2048] (pad 96->128)
  bf16* wT_dt  = (bf16*)(ws + 8912896);    //  0.25 MiB [2048][64]
  bf16* wT_out = (bf16*)(ws + 9175040);    //  4 MiB [1024][2048]
  bf16* wT_ff1 = (bf16*)(ws + 13369344);   // 16 MiB [8192][1024]
  bf16* wT_ff2 = (bf16*)(ws + 30146560);   //  8 MiB [1024][4096]
  bf16* h_bf   = (bf16*)(ws + 38535168);   //  8 MiB (h, later h2)
  float* xcraw = (float*)(ws + 46923776);  // 32 MiB (xc_raw -> dt -> v_bf16)
  bf16* zs     = (bf16*)(ws + 80478208);   // 16 MiB (silu(z) -> out1 f32)
  float* xcf   = (float*)(ws + 97255424);  // 32 MiB xc post-silu f32
  bf16* xcb    = (bf16*)(ws + 130809856);  // 16 MiB (xc bf16 -> y bf16)
  float* dbc   = (float*)(ws + 147587072); //  2 MiB [4096][128]
  bf16* dtlo   = (bf16*)(ws + 149684224);  //  0.5 MiB [4096][64]
  bf16* pbuf   = (bf16*)(ws + 150208512);  // 64 MiB [4096][8192]
  // aliases
  float* dtbuf = xcraw;
  bf16*  vbuf  = (bf16*)xcraw;
  float* out1  = (float*)zs;
  bf16*  ybuf  = xcb;
  bf16*  h2    = h_bf;

  const dim3 tb(256);
  // weight transposes (fp32 -> bf16 [N][K])
  transpose_to_bf16<<<dim3(32, 128), tb, 0, stream>>>(w_in, wT_in, 1024, 4096, 4096);
  transpose_to_bf16<<<dim3(64, 4), tb, 0, stream>>>(w_x, wT_x, 2048, 96, 128);
  transpose_to_bf16<<<dim3(2, 64), tb, 0, stream>>>(w_dt, wT_dt, 64, 2048, 2048);
  transpose_to_bf16<<<dim3(64, 32), tb, 0, stream>>>(w_out, wT_out, 2048, 1024, 1024);
  transpose_to_bf16<<<dim3(32, 256), tb, 0, stream>>>(w_ff1, wT_ff1, 1024, 8192, 8192);
  transpose_to_bf16<<<dim3(128, 32), tb, 0, stream>>>(w_ff2, wT_ff2, 4096, 1024, 1024);

  layernorm_to_bf16<<<kM, tb, 0, stream>>>(x, ln1_g, ln1_b, h_bf);

  // xz = h @ w_in : xc_raw fp32 + silu(z) bf16
  gemm_bt<0><<<dim3(32, 32), tb, 0, stream>>>(h_bf, 1024, wT_in, 1024, 1024,
                                              xcraw, zs, nullptr, nullptr);
  conv_silu<<<(kM * kDI) / 256, tb, 0, stream>>>(xcraw, conv_w, conv_b, xcf, xcb);

  // dbc = xc @ w_x (N padded to 128)
  gemm_bt<1><<<dim3(1, 32), tb, 0, stream>>>(xcb, 2048, wT_x, 2048, 2048,
                                             dbc, dtlo, nullptr, nullptr);
  // dt = softplus(dt_lo @ w_dt + b_dt)
  gemm_bt<2><<<dim3(16, 32), tb, 0, stream>>>(dtlo, 64, wT_dt, 64, 64,
                                              dtbuf, nullptr, b_dt, nullptr);
  mamba_scan<<<256, tb, 0, stream>>>(dtbuf, xcf, dbc, a_log, d_skip, zs, ybuf);

  // out1 = x + y @ w_out
  gemm_bt<3><<<dim3(8, 32), tb, 0, stream>>>(ybuf, 2048, wT_out, 2048, 2048,
                                             out1, nullptr, nullptr, x);
  layernorm_to_bf16<<<kM, tb, 0, stream>>>(out1, ln2_g, ln2_b, h2);

  // p = h2 @ w_ff1 + b_ff1
  gemm_bt<4><<<dim3(64, 32), tb, 0, stream>>>(h2, 1024, wT_ff1, 1024, 1024,
                                              nullptr, pbuf, b_ff1, nullptr);
  geglu<<<(kM * 4096) / 256, tb, 0, stream>>>(pbuf, vbuf);

  // d_out = out1 + v @ w_ff2 + b_ff2
  gemm_bt<5><<<dim3(8, 32), tb, 0, stream>>>(vbuf, 4096, wT_ff2, 4096, 4096,
                                             out, nullptr, b_ff2, out1);
  (void)in_sizes; (void)n_in; (void)out_size; (void)ws_size;
}

// Round 4
// 833.020 us; speedup vs baseline: 1.3129x; 1.3129x over previous
//
#include <hip/hip_runtime.h>
#include <hip/hip_bf16.h>
#include <stdint.h>
#include <stddef.h>

// ---------------------------------------------------------------------------
// BasicMambaBlock on MI355X (gfx950).
// Pipeline: LN1 -> GEMM(w_in) -> conv+silu -> GEMM(w_x) -> GEMM(w_dt)+softplus
//           -> chunked selective scan (p1/p2/p3) -> GEMM(w_out)+res -> LN2
//           -> GEMM(w_ff1)+bias -> geglu -> GEMM(w_ff2)+bias+res.
// All big GEMMs: bf16 MFMA 16x16x32, 128x128 tile, 4 waves, global_load_lds.
// Weights transposed to [N][K] bf16 once per call (inputs restored each call).
// R2: scan was latency-bound (516us, 12% occupancy, 2.9% HBM). Replaced the
//     monolithic scan with a 3-phase chunked linear-recurrence scan:
//     h_end = P*h0 + q per chunk, P = exp(A*sum(dt)) exactly. 16x parallelism.
// ---------------------------------------------------------------------------

typedef __bf16 bf16;
typedef __bf16 bf16x8 __attribute__((ext_vector_type(8)));
typedef float  f32x4  __attribute__((ext_vector_type(4)));

static constexpr int kB  = 2;
static constexpr int kL  = 2048;
static constexpr int kDM = 1024;          // d_model
static constexpr int kDI = 2048;          // d_inner
static constexpr int kM  = kB * kL;       // 4096 rows (B*L)
static constexpr int kNC = 16;            // scan chunks
static constexpr int kCH = kL / kNC;      // 128 steps per chunk

// ---------------- helpers ----------------
__device__ __forceinline__ void gload16(const void* g, void* l) {
  // async global->LDS, 16B per lane; LDS dest = (wave-uniform l) + lane*16
  __builtin_amdgcn_global_load_lds((__attribute__((address_space(1))) void*)g,
                                   (__attribute__((address_space(3))) void*)l,
                                   16, 0, 0);
}

// ---------------- weight transpose fp32[K][N] -> bf16[Npad][K] --------------
__global__ __launch_bounds__(256) void transpose_to_bf16(
    const float* __restrict__ w, bf16* __restrict__ wt, int K, int N, int Npad) {
  __shared__ float t[32][33];
  const int k0 = blockIdx.x * 32, n0 = blockIdx.y * 32;
  const int tx = threadIdx.x & 31, ty = threadIdx.x >> 5;  // 32 x 8
#pragma unroll
  for (int i = ty; i < 32; i += 8) {
    float v = 0.f;
    if (k0 + i < K && n0 + tx < N) v = w[(size_t)(k0 + i) * N + n0 + tx];
    t[i][tx] = v;
  }
  __syncthreads();
#pragma unroll
  for (int i = ty; i < 32; i += 8) {
    const int n = n0 + i, k = k0 + tx;
    if (n < Npad && k < K) wt[(size_t)n * K + k] = (bf16)t[tx][i];
  }
}

// ---------------- layernorm (D=1024) -> bf16 ----------------
__global__ __launch_bounds__(256) void layernorm_to_bf16(
    const float* __restrict__ x, const float* __restrict__ g,
    const float* __restrict__ b, bf16* __restrict__ out) {
  const int row = blockIdx.x;
  const float4 v = ((const float4*)(x + (size_t)row * kDM))[threadIdx.x];
  float s  = v.x + v.y + v.z + v.w;
  float s2 = v.x * v.x + v.y * v.y + v.z * v.z + v.w * v.w;
#pragma unroll
  for (int off = 1; off < 64; off <<= 1) {
    s  += __shfl_xor(s, off);
    s2 += __shfl_xor(s2, off);
  }
  __shared__ float ws[4], ws2[4];
  const int wave = threadIdx.x >> 6, lane = threadIdx.x & 63;
  if (lane == 0) { ws[wave] = s; ws2[wave] = s2; }
  __syncthreads();
  s  = ws[0] + ws[1] + ws[2] + ws[3];
  s2 = ws2[0] + ws2[1] + ws2[2] + ws2[3];
  const float mu  = s * (1.f / kDM);
  const float var = s2 * (1.f / kDM) - mu * mu;
  const float r   = rsqrtf(var + 1e-5f);
  const int c = threadIdx.x * 4;
  const float4 gg = ((const float4*)g)[threadIdx.x];
  const float4 bb = ((const float4*)b)[threadIdx.x];
  bf16* o = out + (size_t)row * kDM + c;
  o[0] = (bf16)((v.x - mu) * r * gg.x + bb.x);
  o[1] = (bf16)((v.y - mu) * r * gg.y + bb.y);
  o[2] = (bf16)((v.z - mu) * r * gg.z + bb.z);
  o[3] = (bf16)((v.w - mu) * r * gg.w + bb.w);
}

// ---------------- bf16 MFMA GEMM: C[M][N] = A[M][K] * BT[N][K]^T ------------
// 128x128 tile, 4 waves (each 64x64 = 4x4 16x16 frags), BK=32, linear LDS,
// global_load_lds width-16 staging (m97 structure).
template <int MODE>
__global__ __launch_bounds__(256, 2) void gemm_bt(
    const bf16* __restrict__ A, int lda,
    const bf16* __restrict__ BT, int ldbt, int K,
    float* __restrict__ C0, bf16* __restrict__ C1,
    const float* __restrict__ bias, const float* __restrict__ res) {
  __shared__ __align__(16) bf16 As[128 * 32];
  __shared__ __align__(16) bf16 Bs[128 * 32];

  const int tid  = threadIdx.x;
  const int wave = tid >> 6;
  const int lane = tid & 63;
  const int m0 = blockIdx.y * 128;
  const int n0 = blockIdx.x * 128;
  const int wr = wave >> 1, wc = wave & 1;       // 2x2 wave grid, 64x64 each
  const int lr = lane & 15, kg = lane >> 4;

  const int srow = lane >> 2;                    // staging row within chunk
  const int scol = (lane & 3) * 8;               // staging col (bf16 elems)

  const bf16* Ag0 = A  + (size_t)(m0 + wave * 32 + srow) * lda  + scol;
  const bf16* Ag1 = Ag0 + (size_t)16 * lda;
  const bf16* Bg0 = BT + (size_t)(n0 + wave * 32 + srow) * ldbt + scol;
  const bf16* Bg1 = Bg0 + (size_t)16 * ldbt;
  bf16* Al0 = As + wave * 1024;  // wave stages rows [32w, 32w+32)
  bf16* Al1 = Al0 + 512;
  bf16* Bl0 = Bs + wave * 1024;
  bf16* Bl1 = Bl0 + 512;

  f32x4 acc[4][4] = {};

  for (int kt = 0; kt < K; kt += 32) {
    __syncthreads();                              // protect LDS from prev reads
    gload16(Ag0 + kt, Al0);
    gload16(Ag1 + kt, Al1);
    gload16(Bg0 + kt, Bl0);
    gload16(Bg1 + kt, Bl1);
    __syncthreads();                              // compiler drains vmcnt here

    bf16x8 af[4], bfr[4];
#pragma unroll
    for (int i = 0; i < 4; ++i) {
      af[i]  = *(const bf16x8*)(As + (wr * 64 + i * 16 + lr) * 32 + kg * 8);
      bfr[i] = *(const bf16x8*)(Bs + (wc * 64 + i * 16 + lr) * 32 + kg * 8);
    }
#pragma unroll
    for (int i = 0; i < 4; ++i)
#pragma unroll
      for (int j = 0; j < 4; ++j)
        acc[i][j] =
            __builtin_amdgcn_mfma_f32_16x16x32_bf16(af[i], bfr[j], acc[i][j], 0, 0, 0);
  }

  // epilogue: C/D layout col=lane&15, row=(lane>>4)*4+e  [verified m89]
#pragma unroll
  for (int i = 0; i < 4; ++i) {
    const int mbase = m0 + wr * 64 + i * 16 + kg * 4;
#pragma unroll
    for (int j = 0; j < 4; ++j) {
      const int n = n0 + wc * 64 + j * 16 + lr;
#pragma unroll
      for (int e = 0; e < 4; ++e) {
        const int m = mbase + e;
        const float v = acc[i][j][e];
        if constexpr (MODE == 0) {        // xz: cols<2048 raw xc, else silu(z)
          if (n < kDI) C0[(size_t)m * kDI + n] = v;
          else         C1[(size_t)m * kDI + (n - kDI)] = (bf16)(v / (1.f + expf(-v)));
        } else if constexpr (MODE == 1) { // dbc fp32 (+ bf16 dt_lo for cols<64)
          C0[(size_t)m * 128 + n] = v;
          if (n < 64) C1[(size_t)m * 64 + n] = (bf16)v;
        } else if constexpr (MODE == 2) { // dt = softplus(v + b_dt)
          const float t = v + bias[n];
          const float sp = (t > 0.f) ? (t + log1pf(expf(-t))) : log1pf(expf(t));
          C0[(size_t)m * kDI + n] = sp;
        } else if constexpr (MODE == 3) { // out1 = x + mamba_out
          C0[(size_t)m * kDM + n] = v + res[(size_t)m * kDM + n];
        } else if constexpr (MODE == 4) { // p = v + b_ff1 (bf16)
          C1[(size_t)m * 8192 + n] = (bf16)(v + bias[n]);
        } else {                          // MODE 5: d_out = v + b_ff2 + out1
          C0[(size_t)m * kDM + n] = v + bias[n] + res[(size_t)m * kDM + n];
        }
      }
    }
  }
}

// ---------------- depthwise causal conv (D_CONV=4) + silu ----------------
__global__ __launch_bounds__(256) void conv_silu(
    const float* __restrict__ xc_raw, const float* __restrict__ cw,
    const float* __restrict__ cb, float* __restrict__ xf, bf16* __restrict__ xb) {
  const int idx = blockIdx.x * 256 + threadIdx.x;  // over M*DI
  const int d = idx & (kDI - 1);
  const int m = idx >> 11;
  const int l = m & (kL - 1);
  float acc = cb[d];
  const float w0 = cw[d * 4 + 0], w1 = cw[d * 4 + 1], w2 = cw[d * 4 + 2],
              w3 = cw[d * 4 + 3];
  if (l >= 3) acc += xc_raw[(size_t)(m - 3) * kDI + d] * w0;
  if (l >= 2) acc += xc_raw[(size_t)(m - 2) * kDI + d] * w1;
  if (l >= 1) acc += xc_raw[(size_t)(m - 1) * kDI + d] * w2;
  acc += xc_raw[(size_t)m * kDI + d] * w3;
  const float a = acc / (1.f + expf(-acc));        // silu
  xf[idx] = a;
  xb[idx] = (bf16)a;
}

// ---------------- chunked selective scan ----------------
// Linear recurrence h_l = dA_l*h_{l-1} + u_l decomposes over chunks:
// h_end = P*h0 + q, P = exp(A*sum(dt)) (exact, one exp), q = scan from 0.
// p1: per-chunk (P,q) in parallel. p2: tiny sequential combine -> h0 per
// chunk. p3: re-run each chunk from its h0, emit y. 16 lanes per (b,d).

__global__ __launch_bounds__(256) void scan_p1(
    const float* __restrict__ dt, const float* __restrict__ xc,
    const float* __restrict__ dbc, const float* __restrict__ a_log,
    float* __restrict__ P, float* __restrict__ Q) {
  const int c  = blockIdx.x & 15;
  const int dg = (blockIdx.x >> 4) & 127;
  const int b  = blockIdx.x >> 11;
  const int dl = threadIdx.x >> 4, n = threadIdx.x & 15;
  const int d  = dg * 16 + dl;
  const float Adn = -expf(a_log[d * 16 + n]);
  const size_t rb = ((size_t)b * kL + c * kCH) * kDI + d;
  const size_t qb = ((size_t)b * kL + c * kCH) * 128 + 64 + n;
  float h = 0.f, sdt = 0.f;
#pragma unroll 8
  for (int l = 0; l < kCH; ++l) {
    const float dtv = dt[rb + (size_t)l * kDI];
    const float xv  = xc[rb + (size_t)l * kDI];
    const float Bv  = dbc[qb + (size_t)l * 128];
    const float dA  = __expf(dtv * Adn);
    h = h * dA + dtv * xv * Bv;
    sdt += dtv;
  }
  const int idx = ((b * kNC + c) * kDI + d) * 16 + n;
  P[idx] = __expf(sdt * Adn);
  Q[idx] = h;
}

__global__ __launch_bounds__(256) void scan_p2(
    const float* __restrict__ P, const float* __restrict__ Q,
    float* __restrict__ H0) {
  const int i  = blockIdx.x * 256 + threadIdx.x;   // over B*DI*16 = 65536
  const int dn = i & (kDI * 16 - 1);
  const int b  = i >> 15;
  float h = 0.f;
#pragma unroll
  for (int c = 0; c < kNC; ++c) {
    const int idx = (b * kNC + c) * (kDI * 16) + dn;
    H0[idx] = h;                        // state at START of chunk c
    h = P[idx] * h + Q[idx];
  }
}

__global__ __launch_bounds__(256) void scan_p3(
    const float* __restrict__ dt, const float* __restrict__ xc,
    const float* __restrict__ dbc, const float* __restrict__ a_log,
    const float* __restrict__ d_skip, const bf16* __restrict__ zs,
    const float* __restrict__ H0, bf16* __restrict__ y) {
  const int c  = blockIdx.x & 15;
  const int dg = (blockIdx.x >> 4) & 127;
  const int b  = blockIdx.x >> 11;
  const int dl = threadIdx.x >> 4, n = threadIdx.x & 15;
  const int d  = dg * 16 + dl;
  const float Adn = -expf(a_log[d * 16 + n]);
  const float dsk = d_skip[d];
  const size_t rb = ((size_t)b * kL + c * kCH) * kDI + d;
  const size_t qb = ((size_t)b * kL + c * kCH) * 128;
  float h = H0[((b * kNC + c) * kDI + d) * 16 + n];
#pragma unroll 4
  for (int l = 0; l < kCH; ++l) {
    const size_t r = rb + (size_t)l * kDI;
    const size_t q = qb + (size_t)l * 128;
    const float dtv = dt[r];
    const float xv  = xc[r];
    const float Bv  = dbc[q + 64 + n];
    const float Cv  = dbc[q + 80 + n];
    const float dA  = __expf(dtv * Adn);
    h = h * dA + dtv * xv * Bv;
    float part = h * Cv;
    part += __shfl_xor(part, 1);
    part += __shfl_xor(part, 2);
    part += __shfl_xor(part, 4);
    part += __shfl_xor(part, 8);
    if (n == 0) {
      y[r] = (bf16)((part + dsk * xv) * (float)zs[r]);
    }
  }
}

// ---------------- geglu: v = a * gelu_tanh(g) ----------------
__global__ __launch_bounds__(256) void geglu(
    const bf16* __restrict__ p, bf16* __restrict__ v) {
  const int idx = blockIdx.x * 256 + threadIdx.x;  // over M*4096
  const int m = idx >> 12, n = idx & 4095;
  const float a = (float)p[(size_t)m * 8192 + n];
  const float g = (float)p[(size_t)m * 8192 + 4096 + n];
  const float g3 = g * g * g;
  const float t  = tanhf(0.7978845608028654f * (g + 0.044715f * g3));
  v[idx] = (bf16)(a * (0.5f * g * (1.f + t)));
}

// ---------------- launch ----------------
extern "C" void kernel_launch(void* const* d_in, const int* in_sizes, int n_in,
                              void* d_out, int out_size, void* d_ws, size_t ws_size,
                              hipStream_t stream) {
  const float* x      = (const float*)d_in[0];
  const float* ln1_g  = (const float*)d_in[1];
  const float* ln1_b  = (const float*)d_in[2];
  const float* w_in   = (const float*)d_in[3];
  const float* conv_w = (const float*)d_in[4];
  const float* conv_b = (const float*)d_in[5];
  const float* w_x    = (const float*)d_in[6];
  const float* w_dt   = (const float*)d_in[7];
  const float* b_dt   = (const float*)d_in[8];
  const float* a_log  = (const float*)d_in[9];
  const float* d_skip = (const float*)d_in[10];
  const float* w_out  = (const float*)d_in[11];
  const float* ln2_g  = (const float*)d_in[12];
  const float* ln2_b  = (const float*)d_in[13];
  const float* w_ff1  = (const float*)d_in[14];
  const float* b_ff1  = (const float*)d_in[15];
  const float* w_ff2  = (const float*)d_in[16];
  const float* b_ff2  = (const float*)d_in[17];
  float* out = (float*)d_out;
  char* ws = (char*)d_ws;

  // arena layout (bytes); lifetimes allow the noted aliasing
  bf16* wT_in  = (bf16*)(ws + 0);          //  8 MiB [4096][1024]
  bf16* wT_x   = (bf16*)(ws + 8388608);    //  0.5 MiB [128][2048] (pad 96->128)
  bf16* wT_dt  = (bf16*)(ws + 8912896);    //  0.25 MiB [2048][64]
  bf16* wT_out = (bf16*)(ws + 9175040);    //  4 MiB [1024][2048]
  bf16* wT_ff1 = (bf16*)(ws + 13369344);   // 16 MiB [8192][1024]
  bf16* wT_ff2 = (bf16*)(ws + 30146560);   //  8 MiB [1024][4096]
  bf16* h_bf   = (bf16*)(ws + 38535168);   //  8 MiB (h, later h2)
  float* xcraw = (float*)(ws + 46923776);  // 32 MiB (xc_raw -> dt -> v_bf16)
  bf16* zs     = (bf16*)(ws + 80478208);   // 16 MiB (silu(z) -> out1 f32)
  float* xcf   = (float*)(ws + 97255424);  // 32 MiB xc post-silu f32
  bf16* xcb    = (bf16*)(ws + 130809856);  // 16 MiB (xc bf16 -> y bf16)
  float* dbc   = (float*)(ws + 147587072); //  2 MiB [4096][128]
  bf16* dtlo   = (bf16*)(ws + 149684224);  //  0.5 MiB [4096][64]
  bf16* pbuf   = (bf16*)(ws + 150208512);  // 64 MiB [4096][8192]
  // aliases
  float* dtbuf = xcraw;
  bf16*  vbuf  = (bf16*)xcraw;
  float* out1  = (float*)zs;
  bf16*  ybuf  = xcb;
  bf16*  h2    = h_bf;
  // scan chunk summaries live in pbuf region (free until ff1): 3 x 4 MiB
  float* Pbuf  = (float*)pbuf;
  float* Qbuf  = (float*)((char*)pbuf + (4 << 20));
  float* H0buf = (float*)((char*)pbuf + (8 << 20));

  const dim3 tb(256);
  // weight transposes (fp32 -> bf16 [N][K])
  transpose_to_bf16<<<dim3(32, 128), tb, 0, stream>>>(w_in, wT_in, 1024, 4096, 4096);
  transpose_to_bf16<<<dim3(64, 4), tb, 0, stream>>>(w_x, wT_x, 2048, 96, 128);
  transpose_to_bf16<<<dim3(2, 64), tb, 0, stream>>>(w_dt, wT_dt, 64, 2048, 2048);
  transpose_to_bf16<<<dim3(64, 32), tb, 0, stream>>>(w_out, wT_out, 2048, 1024, 1024);
  transpose_to_bf16<<<dim3(32, 256), tb, 0, stream>>>(w_ff1, wT_ff1, 1024, 8192, 8192);
  transpose_to_bf16<<<dim3(128, 32), tb, 0, stream>>>(w_ff2, wT_ff2, 4096, 1024, 1024);

  layernorm_to_bf16<<<kM, tb, 0, stream>>>(x, ln1_g, ln1_b, h_bf);

  // xz = h @ w_in : xc_raw fp32 + silu(z) bf16
  gemm_bt<0><<<dim3(32, 32), tb, 0, stream>>>(h_bf, 1024, wT_in, 1024, 1024,
                                              xcraw, zs, nullptr, nullptr);
  conv_silu<<<(kM * kDI) / 256, tb, 0, stream>>>(xcraw, conv_w, conv_b, xcf, xcb);

  // dbc = xc @ w_x (N padded to 128)
  gemm_bt<1><<<dim3(1, 32), tb, 0, stream>>>(xcb, 2048, wT_x, 2048, 2048,
                                             dbc, dtlo, nullptr, nullptr);
  // dt = softplus(dt_lo @ w_dt + b_dt)
  gemm_bt<2><<<dim3(16, 32), tb, 0, stream>>>(dtlo, 64, wT_dt, 64, 64,
                                              dtbuf, nullptr, b_dt, nullptr);

  // chunked scan: p1 (chunk summaries) -> p2 (combine) -> p3 (emit y)
  scan_p1<<<kB * 128 * kNC, tb, 0, stream>>>(dtbuf, xcf, dbc, a_log, Pbuf, Qbuf);
  scan_p2<<<(kB * kDI * 16) / 256, tb, 0, stream>>>(Pbuf, Qbuf, H0buf);
  scan_p3<<<kB * 128 * kNC, tb, 0, stream>>>(dtbuf, xcf, dbc, a_log, d_skip,
                                             zs, H0buf, ybuf);

  // out1 = x + y @ w_out
  gemm_bt<3><<<dim3(8, 32), tb, 0, stream>>>(ybuf, 2048, wT_out, 2048, 2048,
                                             out1, nullptr, nullptr, x);
  layernorm_to_bf16<<<kM, tb, 0, stream>>>(out1, ln2_g, ln2_b, h2);

  // p = h2 @ w_ff1 + b_ff1
  gemm_bt<4><<<dim3(64, 32), tb, 0, stream>>>(h2, 1024, wT_ff1, 1024, 1024,
                                              nullptr, pbuf, b_ff1, nullptr);
  geglu<<<(kM * 4096) / 256, tb, 0, stream>>>(pbuf, vbuf);

  // d_out = out1 + v @ w_ff2 + b_ff2
  gemm_bt<5><<<dim3(8, 32), tb, 0, stream>>>(vbuf, 4096, wT_ff2, 4096, 4096,
                                             out, nullptr, b_ff2, out1);
  (void)in_sizes; (void)n_in; (void)out_size; (void)ws_size;
}

// Round 7
// 687.947 us; speedup vs baseline: 1.5898x; 1.2109x over previous
//
#include <hip/hip_runtime.h>
#include <hip/hip_bf16.h>
#include <stdint.h>
#include <stddef.h>

// ---------------------------------------------------------------------------
// BasicMambaBlock on MI355X (gfx950).
// Pipeline: LN1 -> GEMM(w_in) -> conv+silu -> GEMM(w_x) -> GEMM(w_dt)+softplus
//           -> chunked selective scan (p1/p2/p3) -> GEMM(w_out)+res -> LN2
//           -> GEMM(w_ff1)+bias -> geglu -> GEMM(w_ff2)+bias+res.
// All big GEMMs: bf16 MFMA 16x16x32, 128x128 tile, 4 waves, global_load_lds.
// R2: chunked scan (h_end = P*h0 + q per chunk) for 16x parallelism.
// R5: scan_p3 was 196us (VALU 42%, HBM 4%) — the per-step 4-deep shfl_xor
//     reduction chain + broadcast loads. Restructured: one THREAD per
//     (b,d,chunk) holding all 16 states in regs (static idx), B/C staged in
//     LDS (uniform broadcast reads), NC 16->64 so 4096 waves (16/CU).
// ---------------------------------------------------------------------------

typedef __bf16 bf16;
typedef __bf16 bf16x8 __attribute__((ext_vector_type(8)));
typedef float  f32x4  __attribute__((ext_vector_type(4)));

static constexpr int kB  = 2;
static constexpr int kL  = 2048;
static constexpr int kDM = 1024;          // d_model
static constexpr int kDI = 2048;          // d_inner
static constexpr int kM  = kB * kL;       // 4096 rows (B*L)
static constexpr int kNC = 64;            // scan chunks
static constexpr int kCH = kL / kNC;      // 32 steps per chunk

// ---------------- helpers ----------------
__device__ __forceinline__ void gload16(const void* g, void* l) {
  // async global->LDS, 16B per lane; LDS dest = (wave-uniform l) + lane*16
  __builtin_amdgcn_global_load_lds((__attribute__((address_space(1))) void*)g,
                                   (__attribute__((address_space(3))) void*)l,
                                   16, 0, 0);
}

// ---------------- weight transpose fp32[K][N] -> bf16[Npad][K] --------------
__global__ __launch_bounds__(256) void transpose_to_bf16(
    const float* __restrict__ w, bf16* __restrict__ wt, int K, int N, int Npad) {
  __shared__ float t[32][33];
  const int k0 = blockIdx.x * 32, n0 = blockIdx.y * 32;
  const int tx = threadIdx.x & 31, ty = threadIdx.x >> 5;  // 32 x 8
#pragma unroll
  for (int i = ty; i < 32; i += 8) {
    float v = 0.f;
    if (k0 + i < K && n0 + tx < N) v = w[(size_t)(k0 + i) * N + n0 + tx];
    t[i][tx] = v;
  }
  __syncthreads();
#pragma unroll
  for (int i = ty; i < 32; i += 8) {
    const int n = n0 + i, k = k0 + tx;
    if (n < Npad && k < K) wt[(size_t)n * K + k] = (bf16)t[tx][i];
  }
}

// ---------------- layernorm (D=1024) -> bf16 ----------------
__global__ __launch_bounds__(256) void layernorm_to_bf16(
    const float* __restrict__ x, const float* __restrict__ g,
    const float* __restrict__ b, bf16* __restrict__ out) {
  const int row = blockIdx.x;
  const float4 v = ((const float4*)(x + (size_t)row * kDM))[threadIdx.x];
  float s  = v.x + v.y + v.z + v.w;
  float s2 = v.x * v.x + v.y * v.y + v.z * v.z + v.w * v.w;
#pragma unroll
  for (int off = 1; off < 64; off <<= 1) {
    s  += __shfl_xor(s, off);
    s2 += __shfl_xor(s2, off);
  }
  __shared__ float ws[4], ws2[4];
  const int wave = threadIdx.x >> 6, lane = threadIdx.x & 63;
  if (lane == 0) { ws[wave] = s; ws2[wave] = s2; }
  __syncthreads();
  s  = ws[0] + ws[1] + ws[2] + ws[3];
  s2 = ws2[0] + ws2[1] + ws2[2] + ws2[3];
  const float mu  = s * (1.f / kDM);
  const float var = s2 * (1.f / kDM) - mu * mu;
  const float r   = rsqrtf(var + 1e-5f);
  const int c = threadIdx.x * 4;
  const float4 gg = ((const float4*)g)[threadIdx.x];
  const float4 bb = ((const float4*)b)[threadIdx.x];
  bf16* o = out + (size_t)row * kDM + c;
  o[0] = (bf16)((v.x - mu) * r * gg.x + bb.x);
  o[1] = (bf16)((v.y - mu) * r * gg.y + bb.y);
  o[2] = (bf16)((v.z - mu) * r * gg.z + bb.z);
  o[3] = (bf16)((v.w - mu) * r * gg.w + bb.w);
}

// ---------------- bf16 MFMA GEMM: C[M][N] = A[M][K] * BT[N][K]^T ------------
// 128x128 tile, 4 waves (each 64x64 = 4x4 16x16 frags), BK=32, linear LDS,
// global_load_lds width-16 staging (m97 structure).
template <int MODE>
__global__ __launch_bounds__(256, 2) void gemm_bt(
    const bf16* __restrict__ A, int lda,
    const bf16* __restrict__ BT, int ldbt, int K,
    float* __restrict__ C0, bf16* __restrict__ C1,
    const float* __restrict__ bias, const float* __restrict__ res) {
  __shared__ __align__(16) bf16 As[128 * 32];
  __shared__ __align__(16) bf16 Bs[128 * 32];

  const int tid  = threadIdx.x;
  const int wave = tid >> 6;
  const int lane = tid & 63;
  const int m0 = blockIdx.y * 128;
  const int n0 = blockIdx.x * 128;
  const int wr = wave >> 1, wc = wave & 1;       // 2x2 wave grid, 64x64 each
  const int lr = lane & 15, kg = lane >> 4;

  const int srow = lane >> 2;                    // staging row within chunk
  const int scol = (lane & 3) * 8;               // staging col (bf16 elems)

  const bf16* Ag0 = A  + (size_t)(m0 + wave * 32 + srow) * lda  + scol;
  const bf16* Ag1 = Ag0 + (size_t)16 * lda;
  const bf16* Bg0 = BT + (size_t)(n0 + wave * 32 + srow) * ldbt + scol;
  const bf16* Bg1 = Bg0 + (size_t)16 * ldbt;
  bf16* Al0 = As + wave * 1024;  // wave stages rows [32w, 32w+32)
  bf16* Al1 = Al0 + 512;
  bf16* Bl0 = Bs + wave * 1024;
  bf16* Bl1 = Bl0 + 512;

  f32x4 acc[4][4] = {};

  for (int kt = 0; kt < K; kt += 32) {
    __syncthreads();                              // protect LDS from prev reads
    gload16(Ag0 + kt, Al0);
    gload16(Ag1 + kt, Al1);
    gload16(Bg0 + kt, Bl0);
    gload16(Bg1 + kt, Bl1);
    __syncthreads();                              // compiler drains vmcnt here

    bf16x8 af[4], bfr[4];
#pragma unroll
    for (int i = 0; i < 4; ++i) {
      af[i]  = *(const bf16x8*)(As + (wr * 64 + i * 16 + lr) * 32 + kg * 8);
      bfr[i] = *(const bf16x8*)(Bs + (wc * 64 + i * 16 + lr) * 32 + kg * 8);
    }
#pragma unroll
    for (int i = 0; i < 4; ++i)
#pragma unroll
      for (int j = 0; j < 4; ++j)
        acc[i][j] =
            __builtin_amdgcn_mfma_f32_16x16x32_bf16(af[i], bfr[j], acc[i][j], 0, 0, 0);
  }

  // epilogue: C/D layout col=lane&15, row=(lane>>4)*4+e  [verified m89]
#pragma unroll
  for (int i = 0; i < 4; ++i) {
    const int mbase = m0 + wr * 64 + i * 16 + kg * 4;
#pragma unroll
    for (int j = 0; j < 4; ++j) {
      const int n = n0 + wc * 64 + j * 16 + lr;
#pragma unroll
      for (int e = 0; e < 4; ++e) {
        const int m = mbase + e;
        const float v = acc[i][j][e];
        if constexpr (MODE == 0) {        // xz: cols<2048 raw xc, else silu(z)
          if (n < kDI) C0[(size_t)m * kDI + n] = v;
          else         C1[(size_t)m * kDI + (n - kDI)] = (bf16)(v / (1.f + expf(-v)));
        } else if constexpr (MODE == 1) { // dbc fp32 (+ bf16 dt_lo for cols<64)
          C0[(size_t)m * 128 + n] = v;
          if (n < 64) C1[(size_t)m * 64 + n] = (bf16)v;
        } else if constexpr (MODE == 2) { // dt = softplus(v + b_dt)
          const float t = v + bias[n];
          const float sp = (t > 0.f) ? (t + log1pf(expf(-t))) : log1pf(expf(t));
          C0[(size_t)m * kDI + n] = sp;
        } else if constexpr (MODE == 3) { // out1 = x + mamba_out
          C0[(size_t)m * kDM + n] = v + res[(size_t)m * kDM + n];
        } else if constexpr (MODE == 4) { // p = v + b_ff1 (bf16)
          C1[(size_t)m * 8192 + n] = (bf16)(v + bias[n]);
        } else {                          // MODE 5: d_out = v + b_ff2 + out1
          C0[(size_t)m * kDM + n] = v + bias[n] + res[(size_t)m * kDM + n];
        }
      }
    }
  }
}

// ---------------- depthwise causal conv (D_CONV=4) + silu ----------------
__global__ __launch_bounds__(256) void conv_silu(
    const float* __restrict__ xc_raw, const float* __restrict__ cw,
    const float* __restrict__ cb, float* __restrict__ xf, bf16* __restrict__ xb) {
  const int idx = blockIdx.x * 256 + threadIdx.x;  // over M*DI
  const int d = idx & (kDI - 1);
  const int m = idx >> 11;
  const int l = m & (kL - 1);
  float acc = cb[d];
  const float w0 = cw[d * 4 + 0], w1 = cw[d * 4 + 1], w2 = cw[d * 4 + 2],
              w3 = cw[d * 4 + 3];
  if (l >= 3) acc += xc_raw[(size_t)(m - 3) * kDI + d] * w0;
  if (l >= 2) acc += xc_raw[(size_t)(m - 2) * kDI + d] * w1;
  if (l >= 1) acc += xc_raw[(size_t)(m - 1) * kDI + d] * w2;
  acc += xc_raw[(size_t)m * kDI + d] * w3;
  const float a = acc / (1.f + expf(-acc));        // silu
  xf[idx] = a;
  xb[idx] = (bf16)a;
}

// ---------------- chunked selective scan (one thread per b,d,chunk) --------
// Linear recurrence h_l = dA_l*h_{l-1} + u_l decomposes over chunks:
// h_end = P*h0 + q, P = exp(A*sum(dt)) (exact), q = scan from 0.
// Each thread holds all 16 states in registers (static indexing); B/C staged
// in LDS once per block and read with uniform-address broadcasts.

__global__ __launch_bounds__(256) void scan_p1(
    const float* __restrict__ dt, const float* __restrict__ xc,
    const float* __restrict__ dbc, const float* __restrict__ a_log,
    float* __restrict__ P, float* __restrict__ Q) {
  const int dg = blockIdx.x & 7;                 // d-group (256 channels)
  const int c  = (blockIdx.x >> 3) & (kNC - 1);
  const int b  = blockIdx.x >> 9;
  const int d  = dg * 256 + threadIdx.x;
  __shared__ __align__(16) float BC[kCH][32];    // cols 0-15 = B, 16-31 = C
  {
    const int l  = threadIdx.x >> 3;             // 32 rows x 8 groups
    const int cg = (threadIdx.x & 7) * 4;
    *(float4*)&BC[l][cg] =
        *(const float4*)&dbc[(size_t)(b * kL + c * kCH + l) * 128 + 64 + cg];
  }
  __syncthreads();
  float A[16];
#pragma unroll
  for (int q = 0; q < 4; ++q) {
    const float4 al = *(const float4*)&a_log[d * 16 + q * 4];
    A[q * 4 + 0] = -__expf(al.x);
    A[q * 4 + 1] = -__expf(al.y);
    A[q * 4 + 2] = -__expf(al.z);
    A[q * 4 + 3] = -__expf(al.w);
  }
  float h[16] = {};
  float sdt = 0.f;
  const size_t rb = ((size_t)b * kL + c * kCH) * kDI + d;
#pragma unroll 2
  for (int l = 0; l < kCH; ++l) {
    const float dtv = dt[rb + (size_t)l * kDI];
    const float xv  = xc[rb + (size_t)l * kDI];
    const float u   = dtv * xv;
    sdt += dtv;
    float Bv[16];
    *(float4*)&Bv[0]  = *(const float4*)&BC[l][0];
    *(float4*)&Bv[4]  = *(const float4*)&BC[l][4];
    *(float4*)&Bv[8]  = *(const float4*)&BC[l][8];
    *(float4*)&Bv[12] = *(const float4*)&BC[l][12];
#pragma unroll
    for (int n = 0; n < 16; ++n) {
      const float dA = __expf(dtv * A[n]);
      h[n] = h[n] * dA + u * Bv[n];
    }
  }
  const size_t o = (((size_t)b * kNC + c) * kDI + d) * 16;
  float Pv[16];
#pragma unroll
  for (int n = 0; n < 16; ++n) Pv[n] = __expf(sdt * A[n]);
#pragma unroll
  for (int q = 0; q < 4; ++q) {
    *(float4*)&P[o + q * 4] = *(float4*)&Pv[q * 4];
    *(float4*)&Q[o + q * 4] = *(float4*)&h[q * 4];
  }
}

__global__ __launch_bounds__(256) void scan_p2(
    const float* __restrict__ P, const float* __restrict__ Q,
    float* __restrict__ H0) {
  const int i  = blockIdx.x * 256 + threadIdx.x;   // over B*DI*16 = 65536
  const int dn = i & (kDI * 16 - 1);
  const int b  = i >> 15;
  float h = 0.f;
#pragma unroll 8
  for (int c = 0; c < kNC; ++c) {
    const size_t idx = ((size_t)(b * kNC + c)) * (kDI * 16) + dn;
    H0[idx] = h;                        // state at START of chunk c
    h = P[idx] * h + Q[idx];
  }
}

__global__ __launch_bounds__(256) void scan_p3(
    const float* __restrict__ dt, const float* __restrict__ xc,
    const float* __restrict__ dbc, const float* __restrict__ a_log,
    const float* __restrict__ d_skip, const bf16* __restrict__ zs,
    const float* __restrict__ H0, bf16* __restrict__ y) {
  const int dg = blockIdx.x & 7;
  const int c  = (blockIdx.x >> 3) & (kNC - 1);
  const int b  = blockIdx.x >> 9;
  const int d  = dg * 256 + threadIdx.x;
  __shared__ __align__(16) float BC[kCH][32];
  {
    const int l  = threadIdx.x >> 3;
    const int cg = (threadIdx.x & 7) * 4;
    *(float4*)&BC[l][cg] =
        *(const float4*)&dbc[(size_t)(b * kL + c * kCH + l) * 128 + 64 + cg];
  }
  __syncthreads();
  float A[16];
#pragma unroll
  for (int q = 0; q < 4; ++q) {
    const float4 al = *(const float4*)&a_log[d * 16 + q * 4];
    A[q * 4 + 0] = -__expf(al.x);
    A[q * 4 + 1] = -__expf(al.y);
    A[q * 4 + 2] = -__expf(al.z);
    A[q * 4 + 3] = -__expf(al.w);
  }
  const float dsk = d_skip[d];
  float h[16];
  const size_t o = (((size_t)b * kNC + c) * kDI + d) * 16;
#pragma unroll
  for (int q = 0; q < 4; ++q)
    *(float4*)&h[q * 4] = *(const float4*)&H0[o + q * 4];
  const size_t rb = ((size_t)b * kL + c * kCH) * kDI + d;
#pragma unroll 2
  for (int l = 0; l < kCH; ++l) {
    const size_t r  = rb + (size_t)l * kDI;
    const float dtv = dt[r];
    const float xv  = xc[r];
    const float zv  = (float)zs[r];
    const float u   = dtv * xv;
    float Bv[16], Cv[16];
    *(float4*)&Bv[0]  = *(const float4*)&BC[l][0];
    *(float4*)&Bv[4]  = *(const float4*)&BC[l][4];
    *(float4*)&Bv[8]  = *(const float4*)&BC[l][8];
    *(float4*)&Bv[12] = *(const float4*)&BC[l][12];
    *(float4*)&Cv[0]  = *(const float4*)&BC[l][16];
    *(float4*)&Cv[4]  = *(const float4*)&BC[l][20];
    *(float4*)&Cv[8]  = *(const float4*)&BC[l][24];
    *(float4*)&Cv[12] = *(const float4*)&BC[l][28];
    float pp[4] = {0.f, 0.f, 0.f, 0.f};
#pragma unroll
    for (int n = 0; n < 16; ++n) {
      const float dA = __expf(dtv * A[n]);
      h[n] = h[n] * dA + u * Bv[n];
      pp[n & 3] += h[n] * Cv[n];
    }
    const float part = (pp[0] + pp[1]) + (pp[2] + pp[3]);
    y[r] = (bf16)((part + dsk * xv) * zv);
  }
}

// ---------------- geglu: v = a * gelu_tanh(g) ----------------
__global__ __launch_bounds__(256) void geglu(
    const bf16* __restrict__ p, bf16* __restrict__ v) {
  const int idx = blockIdx.x * 256 + threadIdx.x;  // over M*4096
  const int m = idx >> 12, n = idx & 4095;
  const float a = (float)p[(size_t)m * 8192 + n];
  const float g = (float)p[(size_t)m * 8192 + 4096 + n];
  const float g3 = g * g * g;
  const float t  = tanhf(0.7978845608028654f * (g + 0.044715f * g3));
  v[idx] = (bf16)(a * (0.5f * g * (1.f + t)));
}

// ---------------- launch ----------------
extern "C" void kernel_launch(void* const* d_in, const int* in_sizes, int n_in,
                              void* d_out, int out_size, void* d_ws, size_t ws_size,
                              hipStream_t stream) {
  const float* x      = (const float*)d_in[0];
  const float* ln1_g  = (const float*)d_in[1];
  const float* ln1_b  = (const float*)d_in[2];
  const float* w_in   = (const float*)d_in[3];
  const float* conv_w = (const float*)d_in[4];
  const float* conv_b = (const float*)d_in[5];
  const float* w_x    = (const float*)d_in[6];
  const float* w_dt   = (const float*)d_in[7];
  const float* b_dt   = (const float*)d_in[8];
  const float* a_log  = (const float*)d_in[9];
  const float* d_skip = (const float*)d_in[10];
  const float* w_out  = (const float*)d_in[11];
  const float* ln2_g  = (const float*)d_in[12];
  const float* ln2_b  = (const float*)d_in[13];
  const float* w_ff1  = (const float*)d_in[14];
  const float* b_ff1  = (const float*)d_in[15];
  const float* w_ff2  = (const float*)d_in[16];
  const float* b_ff2  = (const float*)d_in[17];
  float* out = (float*)d_out;
  char* ws = (char*)d_ws;

  // arena layout (bytes); lifetimes allow the noted aliasing
  bf16* wT_in  = (bf16*)(ws + 0);          //  8 MiB [4096][1024]
  bf16* wT_x   = (bf16*)(ws + 8388608);    //  0.5 MiB [128][2048] (pad 96->128)
  bf16* wT_dt  = (bf16*)(ws + 8912896);    //  0.25 MiB [2048][64]
  bf16* wT_out = (bf16*)(ws + 9175040);    //  4 MiB [1024][2048]
  bf16* wT_ff1 = (bf16*)(ws + 13369344);   // 16 MiB [8192][1024]
  bf16* wT_ff2 = (bf16*)(ws + 30146560);   //  8 MiB [1024][4096]
  bf16* h_bf   = (bf16*)(ws + 38535168);   //  8 MiB (h, later h2)
  float* xcraw = (float*)(ws + 46923776);  // 32 MiB (xc_raw -> dt -> v_bf16)
  bf16* zs     = (bf16*)(ws + 80478208);   // 16 MiB (silu(z) -> out1 f32)
  float* xcf   = (float*)(ws + 97255424);  // 32 MiB xc post-silu f32
  bf16* xcb    = (bf16*)(ws + 130809856);  // 16 MiB (xc bf16 -> y bf16)
  float* dbc   = (float*)(ws + 147587072); //  2 MiB [4096][128]
  bf16* dtlo   = (bf16*)(ws + 149684224);  //  0.5 MiB [4096][64]
  bf16* pbuf   = (bf16*)(ws + 150208512);  // 64 MiB [4096][8192]
  // aliases
  float* dtbuf = xcraw;
  bf16*  vbuf  = (bf16*)xcraw;
  float* out1  = (float*)zs;
  bf16*  ybuf  = xcb;
  bf16*  h2    = h_bf;
  // scan chunk summaries live in pbuf region (free until ff1): 3 x 16 MiB
  float* Pbuf  = (float*)pbuf;
  float* Qbuf  = (float*)((char*)pbuf + (16 << 20));
  float* H0buf = (float*)((char*)pbuf + (32 << 20));

  const dim3 tb(256);
  // weight transposes (fp32 -> bf16 [N][K])
  transpose_to_bf16<<<dim3(32, 128), tb, 0, stream>>>(w_in, wT_in, 1024, 4096, 4096);
  transpose_to_bf16<<<dim3(64, 4), tb, 0, stream>>>(w_x, wT_x, 2048, 96, 128);
  transpose_to_bf16<<<dim3(2, 64), tb, 0, stream>>>(w_dt, wT_dt, 64, 2048, 2048);
  transpose_to_bf16<<<dim3(64, 32), tb, 0, stream>>>(w_out, wT_out, 2048, 1024, 1024);
  transpose_to_bf16<<<dim3(32, 256), tb, 0, stream>>>(w_ff1, wT_ff1, 1024, 8192, 8192);
  transpose_to_bf16<<<dim3(128, 32), tb, 0, stream>>>(w_ff2, wT_ff2, 4096, 1024, 1024);

  layernorm_to_bf16<<<kM, tb, 0, stream>>>(x, ln1_g, ln1_b, h_bf);

  // xz = h @ w_in : xc_raw fp32 + silu(z) bf16
  gemm_bt<0><<<dim3(32, 32), tb, 0, stream>>>(h_bf, 1024, wT_in, 1024, 1024,
                                              xcraw, zs, nullptr, nullptr);
  conv_silu<<<(kM * kDI) / 256, tb, 0, stream>>>(xcraw, conv_w, conv_b, xcf, xcb);

  // dbc = xc @ w_x (N padded to 128)
  gemm_bt<1><<<dim3(1, 32), tb, 0, stream>>>(xcb, 2048, wT_x, 2048, 2048,
                                             dbc, dtlo, nullptr, nullptr);
  // dt = softplus(dt_lo @ w_dt + b_dt)
  gemm_bt<2><<<dim3(16, 32), tb, 0, stream>>>(dtlo, 64, wT_dt, 64, 64,
                                              dtbuf, nullptr, b_dt, nullptr);

  // chunked scan: p1 (chunk summaries) -> p2 (combine) -> p3 (emit y)
  scan_p1<<<kB * kNC * (kDI / 256), tb, 0, stream>>>(dtbuf, xcf, dbc, a_log,
                                                     Pbuf, Qbuf);
  scan_p2<<<(kB * kDI * 16) / 256, tb, 0, stream>>>(Pbuf, Qbuf, H0buf);
  scan_p3<<<kB * kNC * (kDI / 256), tb, 0, stream>>>(dtbuf, xcf, dbc, a_log,
                                                     d_skip, zs, H0buf, ybuf);

  // out1 = x + y @ w_out
  gemm_bt<3><<<dim3(8, 32), tb, 0, stream>>>(ybuf, 2048, wT_out, 2048, 2048,
                                             out1, nullptr, nullptr, x);
  layernorm_to_bf16<<<kM, tb, 0, stream>>>(out1, ln2_g, ln2_b, h2);

  // p = h2 @ w_ff1 + b_ff1
  gemm_bt<4><<<dim3(64, 32), tb, 0, stream>>>(h2, 1024, wT_ff1, 1024, 1024,
                                              nullptr, pbuf, b_ff1, nullptr);
  geglu<<<(kM * 4096) / 256, tb, 0, stream>>>(pbuf, vbuf);

  // d_out = out1 + v @ w_ff2 + b_ff2
  gemm_bt<5><<<dim3(8, 32), tb, 0, stream>>>(vbuf, 4096, wT_ff2, 4096, 4096,
                                             out, nullptr, b_ff2, out1);
  (void)in_sizes; (void)n_in; (void)out_size; (void)ws_size;
}